// Round 10
// baseline (394.911 us; speedup 1.0000x reference)
//
#include <hip/hip_runtime.h>
#include <hip/hip_cooperative_groups.h>
#include <hip/hip_bf16.h>
#include <hip/hip_fp16.h>
#include <math.h>

namespace cg = cooperative_groups;

#define N_SEQ 512
#define DIM   1024
#define HEADS 16
#define DH    64
#define P     32
#define PSTR  520   // prob LDS row stride in halfs

#define SMEM_BYTES 54656

typedef short    bf16x8 __attribute__((ext_vector_type(8)));
typedef _Float16 f16x8  __attribute__((ext_vector_type(8)));
typedef float    f32x4  __attribute__((ext_vector_type(4)));

__device__ inline unsigned short f2bf(float f) {
  union { float f; unsigned u; } v; v.f = f;
  unsigned r = (v.u + 0x7fffu + ((v.u >> 16) & 1u)) >> 16;
  return (unsigned short)r;
}

union H8 { f16x8 v; __half2 h2[4]; unsigned u32[4]; };

__device__ inline float rowscore(const H8& a, const H8& c, f16x8 w2f,
                                 float4 b2q, float4 w3q) {
  H8 u;
#pragma unroll
  for (int k = 0; k < 4; ++k) {
    const __half2 s = __hadd2(a.h2[k], c.h2[k]);
    union { __half2 h; unsigned u; } cv; cv.h = s;
    const unsigned msk = (cv.u >> 15) & 0x00010001u;
    u.u32[k] = cv.u & ~(msk * 0xFFFFu);          // packed relu
  }
  f32x4 acc = {0.f, 0.f, 0.f, 0.f};
  acc = __builtin_amdgcn_mfma_f32_16x16x32_f16(w2f, u.v, acc, 0, 0, 0);
  return fmaxf(acc[0] + b2q.x, 0.f) * w3q.x + fmaxf(acc[1] + b2q.y, 0.f) * w3q.y
       + fmaxf(acc[2] + b2q.z, 0.f) * w3q.z + fmaxf(acc[3] + b2q.w, 0.f) * w3q.w;
}

__device__ inline float quadreduce4(float p0, float p1, float p2, float p3,
                                    int quad) {
  const float sx = (quad & 1) ? p0 : p1;
  const float sy = (quad & 1) ? p2 : p3;
  const float rx = __shfl_xor(sx, 16);
  const float ry = __shfl_xor(sy, 16);
  const float aa = ((quad & 1) ? p1 : p0) + rx;
  const float bb = ((quad & 1) ? p3 : p2) + ry;
  const float sz = (quad & 2) ? aa : bb;
  const float rz = __shfl_xor(sz, 32);
  return ((quad & 2) ? bb : aa) + rz;
}

// ======================= phase 0: prep (256 blocks) ========================
__device__ void phase_prep(int bx, int tid, char* smem,
                           const float* Wqkv, const float* Wq, const float* bq,
                           const float* Wk, const float* bk, const float* W1,
                           const float* x, const float* Wout,
                           short* Wcomb, short* xb, short* Woutb,
                           float* ba32, float* bc32) {
  float* W1s = (float*)smem;          // 32*33
  float* Wqs = W1s + 32 * 33;         // 32*65
  float* wsm = Wqs + 32 * 65;         // 32*65
  float* qs  = wsm + 32 * 65;         // 64*132

  const int part = bx >> 7, rem = bx & 127;
  const int h = rem >> 3, c0 = (rem & 7) * 128;
  const int grow = part * 16 + h;
  for (int idx = tid; idx < 1024; idx += 256)
    W1s[(idx >> 5) * 33 + (idx & 31)] =
        W1[(idx >> 5) * 64 + part * 32 + (idx & 31)];
  const float* Wsel = part ? Wk : Wq;
  for (int idx = tid; idx < 2048; idx += 256)
    Wqs[(idx >> 6) * 65 + (idx & 63)] = Wsel[idx];
  for (int idx = tid; idx < 2048; idx += 256) {
    const int d = idx >> 5, c4 = idx & 31;
    *(float4*)&qs[d * 132 + c4 * 4] =
        *(const float4*)(Wqkv + (size_t)(d * 48 + grow) * DIM + c0 + c4 * 4);
  }
  __syncthreads();
  for (int idx = tid; idx < 2048; idx += 256) {
    const int q = idx >> 6, d = idx & 63;
    float s = 0.f;
#pragma unroll
    for (int p = 0; p < 32; ++p) s += W1s[q * 33 + p] * Wqs[p * 65 + d];
    wsm[q * 65 + d] = s;
  }
  __syncthreads();
  for (int idx = tid; idx < 4096; idx += 256) {
    const int q = idx >> 7, c = idx & 127;
    float s = 0.f;
#pragma unroll
    for (int d = 0; d < 64; ++d) s += wsm[q * 65 + d] * qs[d * 132 + c];
    Wcomb[(size_t)(part * 512 + h * 32 + q) * DIM + c0 + c] = (short)f2bf(s);
  }
  if (rem == 0 && tid < 32) {
    const float* bsel = part ? bk : bq;
    float s = 0.f;
#pragma unroll
    for (int p = 0; p < 32; ++p) s += W1s[tid * 33 + p] * bsel[p];
    (part ? bc32 : ba32)[tid] = s;
  }

  // v-rows of Wcomb: 1024 rows, 4 per block
#pragma unroll
  for (int rr = 0; rr < 4; ++rr) {
    const int ov = bx * 4 + rr;
    const int vh = ov >> 6, vd = ov & 63;
    const float4 v = *(const float4*)(Wqkv + (size_t)(vd * 48 + 32 + vh) * DIM + tid * 4);
    ushort4 o;
    o.x = f2bf(v.x); o.y = f2bf(v.y); o.z = f2bf(v.z); o.w = f2bf(v.w);
    *(ushort4*)(Wcomb + (size_t)(1024 + ov) * DIM + tid * 4) = o;
  }
  // x cast: 131072 float4
  {
    const int idx = bx * 256 + tid;
#pragma unroll
    for (int u = 0; u < 2; ++u) {
      const int t = u * 65536 + idx;
      const float4 v = ((const float4*)x)[t];
      ushort4 o;
      o.x = f2bf(v.x); o.y = f2bf(v.y); o.z = f2bf(v.z); o.w = f2bf(v.w);
      ((ushort4*)xb)[t] = o;
    }
  }
  // Wout cast: 262144 float4
  {
    const int idx = bx * 256 + tid;
#pragma unroll
    for (int u = 0; u < 4; ++u) {
      const int t = u * 65536 + idx;
      const float4 v = ((const float4*)Wout)[t];
      ushort4 o;
      o.x = f2bf(v.x); o.y = f2bf(v.y); o.z = f2bf(v.z); o.w = f2bf(v.w);
      ((ushort4*)Woutb)[t] = o;
    }
  }
}

// ================== phase 1: gemm_acv (256 blocks, x2 rep) =================
__device__ void phase_acv(int bx, int tid,
                          const short* xb, const short* Wcomb,
                          const float* ba32, const float* bc32,
                          const float* b1,
                          __half* a_buf, __half* cb_buf, __half* vT) {
  const int wave0 = bx * 4 + (tid >> 6);
  const int lane = tid & 63;
  const int m = lane & 15;
  const int quad = lane >> 4;

#pragma unroll
  for (int rep = 0; rep < 2; ++rep) {
    const int wv = wave0 + rep * 1024;
    const int tm = wv >> 6;
    const int tn = wv & 63;

    const short* pa  = xb + (size_t)(tm * 16 + m) * DIM + quad * 8;
    const short* pb0 = Wcomb + (size_t)(tn * 32 + m) * DIM + quad * 8;
    const short* pb1 = pb0 + (size_t)16 * DIM;

    f32x4 acc0 = {0.f,0.f,0.f,0.f}, acc1 = {0.f,0.f,0.f,0.f};
#pragma unroll 4
    for (int k = 0; k < DIM; k += 32) {
      const bf16x8 av = *(const bf16x8*)(pa + k);
      const bf16x8 b0 = *(const bf16x8*)(pb0 + k);
      const bf16x8 b1v = *(const bf16x8*)(pb1 + k);
      acc0 = __builtin_amdgcn_mfma_f32_16x16x32_bf16(av, b0, acc0, 0, 0, 0);
      acc1 = __builtin_amdgcn_mfma_f32_16x16x32_bf16(av, b1v, acc1, 0, 0, 0);
    }

#pragma unroll
    for (int r = 0; r < 4; ++r) {
      const int n = tm * 16 + quad * 4 + r;
#pragma unroll
      for (int half = 0; half < 2; ++half) {
        const int o = tn * 32 + m + half * 16;
        const float val = half ? acc1[r] : acc0[r];
        if (o < 512) {
          const int h = o >> 5, q = o & 31;
          a_buf[((size_t)h * N_SEQ + n) * P + q] = __float2half(val + ba32[q]);
        } else if (o < 1024) {
          const int oo = o - 512, h = oo >> 5, q = oo & 31;
          cb_buf[((size_t)h * N_SEQ + n) * P + q] =
              __float2half(val + bc32[q] + b1[q]);
        } else {
          const int ov = o - 1024, h = ov >> 6, d = ov & 63;
          vT[((size_t)h * DH + d) * N_SEQ + n] = __float2half(val);
        }
      }
    }
  }
}

// ===================== phase 2: attention (256 blocks) =====================
__device__ void phase_attn(int bx, int tid, char* smem,
                           const __half* a_buf, const __half* cb_buf,
                           const float* W2, const float* b2, const float* W3,
                           const __half* vT, short* attnb) {
  __half* probS = (__half*)smem;
  float* invS = (float*)(smem + 32 * PSTR * 2);

  const int p = bx & 15;
  const int h = bx >> 4;
  const int w = tid >> 6;
  const int lane = tid & 63;
  const int m = lane & 15, quad = lane >> 4;

  const int tlo = p, thi = 31 - p;
  const int nlo = p + 1, nhi = 32 - p;

  {
    f16x8 w2f;
    {
      const float4* wp = (const float4*)(W2 + m * P + quad * 8);
      const float4 w0 = wp[0], w1 = wp[1];
      H8 u;
      u.h2[0] = __floats2half2_rn(w0.x, w0.y);
      u.h2[1] = __floats2half2_rn(w0.z, w0.w);
      u.h2[2] = __floats2half2_rn(w1.x, w1.y);
      u.h2[3] = __floats2half2_rn(w1.z, w1.w);
      w2f = u.v;
    }
    const float4 b2q = *(const float4*)(b2 + quad * 4);
    const float4 w3q = *(const float4*)(W3 + quad * 4);

    H8 alo[4], ahi[4];
#pragma unroll
    for (int r = 0; r < 4; ++r) {
      alo[r].v = *(const f16x8*)(a_buf + ((size_t)h * N_SEQ + tlo * 16 + 4 * w + r) * P + quad * 8);
      ahi[r].v = *(const f16x8*)(a_buf + ((size_t)h * N_SEQ + thi * 16 + 4 * w + r) * P + quad * 8);
    }

    for (int jt = 0; jt < nhi; ++jt) {
      H8 cb;
      cb.v = *(const f16x8*)(cb_buf + ((size_t)h * N_SEQ + jt * 16 + m) * P + quad * 8);
      const float q0 = rowscore(ahi[0], cb, w2f, b2q, w3q);
      const float q1 = rowscore(ahi[1], cb, w2f, b2q, w3q);
      const float q2 = rowscore(ahi[2], cb, w2f, b2q, w3q);
      const float q3 = rowscore(ahi[3], cb, w2f, b2q, w3q);
      const float fh = quadreduce4(q0, q1, q2, q3, quad);
      probS[(16 + 4 * w + quad) * PSTR + jt * 16 + m] = __float2half(fh);
      if (jt < nlo) {
        const float s0 = rowscore(alo[0], cb, w2f, b2q, w3q);
        const float s1 = rowscore(alo[1], cb, w2f, b2q, w3q);
        const float s2 = rowscore(alo[2], cb, w2f, b2q, w3q);
        const float s3 = rowscore(alo[3], cb, w2f, b2q, w3q);
        const float fl = quadreduce4(s0, s1, s2, s3, quad);
        probS[(4 * w + quad) * PSTR + jt * 16 + m] = __float2half(fl);
      }
    }
  }
  __syncthreads();

  {
    const int lr = 8 * w + (lane >> 3);
    const int c  = lane & 7;
    const int gi = (lr < 16) ? (tlo * 16 + lr) : (thi * 16 + (lr - 16));
    float mx = -1e30f;
#pragma unroll
    for (int k = 0; k < 8; ++k) {
      const int c0 = k * 64 + c * 8;
      if (c0 > gi) break;
      H8 vv; vv.v = *(const f16x8*)&probS[lr * PSTR + c0];
#pragma unroll
      for (int u = 0; u < 8; ++u) {
        const float s = __half2float(vv.h2[u >> 1].data[u & 1]);
        if (c0 + u <= gi) mx = fmaxf(mx, s);
      }
    }
#pragma unroll
    for (int msk = 1; msk < 8; msk <<= 1) mx = fmaxf(mx, __shfl_xor(mx, msk));
    float sum = 0.f;
#pragma unroll
    for (int k = 0; k < 8; ++k) {
      const int c0 = k * 64 + c * 8;
      H8 vv; vv.v = *(const f16x8*)&probS[lr * PSTR + c0];
      H8 o;
#pragma unroll
      for (int u = 0; u < 4; ++u) {
        float e0 = 0.f, e1 = 0.f;
        if (c0 + 2 * u <= gi) {
          e0 = __expf(__half2float(vv.h2[u].data[0]) - mx);
          if (c0 + 2 * u + 1 <= gi)
            e1 = __expf(__half2float(vv.h2[u].data[1]) - mx);
        }
        sum += e0 + e1;
        o.h2[u] = __floats2half2_rn(e0, e1);
      }
      *(f16x8*)&probS[lr * PSTR + c0] = o.v;
    }
#pragma unroll
    for (int msk = 1; msk < 8; msk <<= 1) sum += __shfl_xor(sum, msk);
    if (c == 0) invS[lr] = 1.f / sum;
  }
  __syncthreads();

  {
    const int d0 = w * 16;
    const __half* pb = vT + ((size_t)h * DH + d0 + m) * N_SEQ + quad * 8;
#pragma unroll
    for (int half = 0; half < 2; ++half) {
      const int lbase = half ? 16 : 0;
      const int tile = half ? thi : tlo;
      const int nk = half ? ((33 - p) >> 1) : ((p + 2) >> 1);
      f32x4 acc = {0.f, 0.f, 0.f, 0.f};
      for (int k = 0; k < nk; ++k) {
        const f16x8 a = *(const f16x8*)&probS[(lbase + m) * PSTR + k * 32 + quad * 8];
        const f16x8 b = *(const f16x8*)(pb + k * 32);
        acc = __builtin_amdgcn_mfma_f32_16x16x32_f16(a, b, acc, 0, 0, 0);
      }
#pragma unroll
      for (int r = 0; r < 4; ++r) {
        const int lrow = quad * 4 + r;
        const float val = acc[r] * invS[lbase + lrow];
        attnb[(size_t)(tile * 16 + lrow) * DIM + h * DH + d0 + m] =
            (short)f2bf(val);
      }
    }
  }
}

// =================== phase 3: gemm_out (256 blocks, x2) ====================
__device__ void phase_out(int bx, int tid, const short* attnb,
                          const short* Woutb, float* out) {
  const int wave0 = bx * 4 + (tid >> 6);
  const int lane = tid & 63;
  const int m = lane & 15, quad = lane >> 4;

#pragma unroll
  for (int rep = 0; rep < 2; ++rep) {
    const int wv = wave0 + rep * 1024;
    const int tm = wv >> 6;
    const int tn = wv & 63;

    const short* pa = attnb + (size_t)(tm * 16 + m) * DIM + quad * 8;
    const short* pb = Woutb + (size_t)(tn * 16 + m) * DIM + quad * 8;

    f32x4 acc = {0.f, 0.f, 0.f, 0.f};
#pragma unroll 4
    for (int k = 0; k < DIM; k += 32) {
      const bf16x8 a = *(const bf16x8*)(pa + k);
      const bf16x8 b = *(const bf16x8*)(pb + k);
      acc = __builtin_amdgcn_mfma_f32_16x16x32_bf16(a, b, acc, 0, 0, 0);
    }
#pragma unroll
    for (int r = 0; r < 4; ++r)
      out[(size_t)(tm * 16 + quad * 4 + r) * DIM + tn * 16 + m] = acc[r];
  }
}

// ===================== cooperative all-in-one kernel =======================
__global__ __launch_bounds__(256) void fused_all(
    const float* __restrict__ Wqkv, const float* __restrict__ Wq,
    const float* __restrict__ bq, const float* __restrict__ Wk,
    const float* __restrict__ bk, const float* __restrict__ W1,
    const float* __restrict__ x, const float* __restrict__ Wout,
    const float* __restrict__ b1, const float* __restrict__ W2,
    const float* __restrict__ b2, const float* __restrict__ W3,
    short* __restrict__ Wcomb, short* __restrict__ xb,
    short* __restrict__ Woutb, float* __restrict__ ba32,
    float* __restrict__ bc32, __half* __restrict__ a_buf,
    __half* __restrict__ cb_buf, __half* __restrict__ vT,
    short* __restrict__ attnb, float* __restrict__ out) {
  cg::grid_group grid = cg::this_grid();
  const int bx = blockIdx.x;          // 0..255
  const int tid = threadIdx.x;
  __shared__ __align__(16) char smem[SMEM_BYTES];

  phase_prep(bx, tid, smem, Wqkv, Wq, bq, Wk, bk, W1, x, Wout,
             Wcomb, xb, Woutb, ba32, bc32);
  __threadfence();
  grid.sync();

  phase_acv(bx, tid, xb, Wcomb, ba32, bc32, b1, a_buf, cb_buf, vT);
  __threadfence();
  grid.sync();

  __syncthreads();   // ensure no lingering smem use before attn reuses it
  phase_attn(bx, tid, smem, a_buf, cb_buf, W2, b2, W3, vT, attnb);
  __threadfence();
  grid.sync();

  phase_out(bx, tid, attnb, Woutb, out);
}

// ======================= standalone fallback kernels =======================
__global__ __launch_bounds__(256) void k_prep(
    const float* Wqkv, const float* Wq, const float* bq, const float* Wk,
    const float* bk, const float* W1, const float* x, const float* Wout,
    short* Wcomb, short* xb, short* Woutb, float* ba32, float* bc32) {
  __shared__ __align__(16) char smem[SMEM_BYTES];
  phase_prep(blockIdx.x, threadIdx.x, smem, Wqkv, Wq, bq, Wk, bk, W1, x, Wout,
             Wcomb, xb, Woutb, ba32, bc32);
}
__global__ __launch_bounds__(256) void k_acv(
    const short* xb, const short* Wcomb, const float* ba32, const float* bc32,
    const float* b1, __half* a_buf, __half* cb_buf, __half* vT) {
  phase_acv(blockIdx.x, threadIdx.x, xb, Wcomb, ba32, bc32, b1,
            a_buf, cb_buf, vT);
}
__global__ __launch_bounds__(256) void k_attn(
    const __half* a_buf, const __half* cb_buf, const float* W2,
    const float* b2, const float* W3, const __half* vT, short* attnb) {
  __shared__ __align__(16) char smem[SMEM_BYTES];
  phase_attn(blockIdx.x, threadIdx.x, smem, a_buf, cb_buf, W2, b2, W3, vT,
             attnb);
}
__global__ __launch_bounds__(256) void k_out(
    const short* attnb, const short* Woutb, float* out) {
  phase_out(blockIdx.x, threadIdx.x, attnb, Woutb, out);
}

// ---------------------------------------------------------------------------
extern "C" void kernel_launch(void* const* d_in, const int* in_sizes, int n_in,
                              void* d_out, int out_size, void* d_ws, size_t ws_size,
                              hipStream_t stream) {
  const float* x    = (const float*)d_in[0];
  const float* Wqkv = (const float*)d_in[1];
  const float* Wout = (const float*)d_in[2];
  const float* Wq   = (const float*)d_in[3];
  const float* bq   = (const float*)d_in[4];
  const float* Wk   = (const float*)d_in[5];
  const float* bk   = (const float*)d_in[6];
  const float* W1   = (const float*)d_in[7];
  const float* b1   = (const float*)d_in[8];
  const float* W2   = (const float*)d_in[9];
  const float* b2   = (const float*)d_in[10];
  const float* W3   = (const float*)d_in[11];
  float* out = (float*)d_out;

  float*  ws     = (float*)d_ws;
  float*  ba32   = ws;                                   // 32
  float*  bc32   = ba32 + 32;                            // 32
  __half* a_buf  = (__half*)(bc32 + 32);                 // 16*512*32
  __half* cb_buf = a_buf + (size_t)HEADS * N_SEQ * P;    // 16*512*32
  __half* vT     = cb_buf + (size_t)HEADS * N_SEQ * P;   // 16*64*512
  short*  Wcomb  = (short*)(vT + (size_t)HEADS * DH * N_SEQ); // 2048*1024
  short*  xb     = Wcomb + (size_t)2048 * DIM;           // 512*1024
  short*  Woutb  = xb + (size_t)N_SEQ * DIM;             // 1024*1024
  short*  attnb  = Woutb + (size_t)DIM * DIM;            // 512*1024

  void* args[] = {&Wqkv, &Wq, &bq, &Wk, &bk, &W1, &x, &Wout, &b1, &W2, &b2,
                  &W3, &Wcomb, &xb, &Woutb, &ba32, &bc32, &a_buf, &cb_buf,
                  &vT, &attnb, &out};
  hipError_t e = hipLaunchCooperativeKernel((void*)fused_all, dim3(256),
                                            dim3(256), args, 0, stream);
  if (e != hipSuccess) {
    // fallback: same phases as 4 ordinary launches
    k_prep<<<256, 256, 0, stream>>>(Wqkv, Wq, bq, Wk, bk, W1, x, Wout,
                                    Wcomb, xb, Woutb, ba32, bc32);
    k_acv<<<256, 256, 0, stream>>>(xb, Wcomb, ba32, bc32, b1,
                                   a_buf, cb_buf, vT);
    k_attn<<<256, 256, 0, stream>>>(a_buf, cb_buf, W2, b2, W3, vT, attnb);
    k_out<<<256, 256, 0, stream>>>(attnb, Woutb, out);
  }
}

// Round 11
// 182.251 us; speedup vs baseline: 2.1669x; 2.1669x over previous
//
#include <hip/hip_runtime.h>
#include <hip/hip_bf16.h>
#include <hip/hip_fp16.h>
#include <math.h>

#define N_SEQ 512
#define DIM   1024
#define HEADS 16
#define DH    64
#define P     32
#define PSTR  520   // prob LDS row stride in halfs

#define SMEM_BYTES 54656

typedef short    bf16x8 __attribute__((ext_vector_type(8)));
typedef _Float16 f16x8  __attribute__((ext_vector_type(8)));
typedef float    f32x4  __attribute__((ext_vector_type(4)));

__device__ inline unsigned short f2bf(float f) {
  union { float f; unsigned u; } v; v.f = f;
  unsigned r = (v.u + 0x7fffu + ((v.u >> 16) & 1u)) >> 16;
  return (unsigned short)r;
}

union H8 { f16x8 v; __half2 h2[4]; unsigned u32[4]; };

__device__ inline float rowscore(const H8& a, const H8& c, f16x8 w2f,
                                 float4 b2q, float4 w3q) {
  H8 u;
#pragma unroll
  for (int k = 0; k < 4; ++k) {
    const __half2 s = __hadd2(a.h2[k], c.h2[k]);
    union { __half2 h; unsigned u; } cv; cv.h = s;
    const unsigned msk = (cv.u >> 15) & 0x00010001u;
    u.u32[k] = cv.u & ~(msk * 0xFFFFu);          // packed relu
  }
  f32x4 acc = {0.f, 0.f, 0.f, 0.f};
  acc = __builtin_amdgcn_mfma_f32_16x16x32_f16(w2f, u.v, acc, 0, 0, 0);
  return fmaxf(acc[0] + b2q.x, 0.f) * w3q.x + fmaxf(acc[1] + b2q.y, 0.f) * w3q.y
       + fmaxf(acc[2] + b2q.z, 0.f) * w3q.z + fmaxf(acc[3] + b2q.w, 0.f) * w3q.w;
}

__device__ inline float quadreduce4(float p0, float p1, float p2, float p3,
                                    int quad) {
  const float sx = (quad & 1) ? p0 : p1;
  const float sy = (quad & 1) ? p2 : p3;
  const float rx = __shfl_xor(sx, 16);
  const float ry = __shfl_xor(sy, 16);
  const float aa = ((quad & 1) ? p1 : p0) + rx;
  const float bb = ((quad & 1) ? p3 : p2) + ry;
  const float sz = (quad & 2) ? aa : bb;
  const float rz = __shfl_xor(sz, 32);
  return ((quad & 2) ? bb : aa) + rz;
}

// ======================= kernel 1: prep (256 blocks) =======================
__global__ __launch_bounds__(256) void k_prep(
    const float* __restrict__ Wqkv, const float* __restrict__ Wq,
    const float* __restrict__ bq, const float* __restrict__ Wk,
    const float* __restrict__ bk, const float* __restrict__ W1,
    const float* __restrict__ x, const float* __restrict__ Wout,
    short* __restrict__ Wcomb, short* __restrict__ xb,
    short* __restrict__ Woutb, float* __restrict__ ba32,
    float* __restrict__ bc32) {
  __shared__ __align__(16) char smem[SMEM_BYTES];
  float* W1s = (float*)smem;          // 32*33
  float* Wqs = W1s + 32 * 33;         // 32*65
  float* wsm = Wqs + 32 * 65;         // 32*65
  float* qs  = wsm + 32 * 65;         // 64*132
  const int bx = blockIdx.x, tid = threadIdx.x;

  const int part = bx >> 7, rem = bx & 127;
  const int h = rem >> 3, c0 = (rem & 7) * 128;
  const int grow = part * 16 + h;
  for (int idx = tid; idx < 1024; idx += 256)
    W1s[(idx >> 5) * 33 + (idx & 31)] =
        W1[(idx >> 5) * 64 + part * 32 + (idx & 31)];
  const float* Wsel = part ? Wk : Wq;
  for (int idx = tid; idx < 2048; idx += 256)
    Wqs[(idx >> 6) * 65 + (idx & 63)] = Wsel[idx];
  for (int idx = tid; idx < 2048; idx += 256) {
    const int d = idx >> 5, c4 = idx & 31;
    *(float4*)&qs[d * 132 + c4 * 4] =
        *(const float4*)(Wqkv + (size_t)(d * 48 + grow) * DIM + c0 + c4 * 4);
  }
  __syncthreads();
  for (int idx = tid; idx < 2048; idx += 256) {
    const int q = idx >> 6, d = idx & 63;
    float s = 0.f;
#pragma unroll
    for (int p = 0; p < 32; ++p) s += W1s[q * 33 + p] * Wqs[p * 65 + d];
    wsm[q * 65 + d] = s;
  }
  __syncthreads();
  for (int idx = tid; idx < 4096; idx += 256) {
    const int q = idx >> 7, c = idx & 127;
    float s = 0.f;
#pragma unroll
    for (int d = 0; d < 64; ++d) s += wsm[q * 65 + d] * qs[d * 132 + c];
    Wcomb[(size_t)(part * 512 + h * 32 + q) * DIM + c0 + c] = (short)f2bf(s);
  }
  if (rem == 0 && tid < 32) {
    const float* bsel = part ? bk : bq;
    float s = 0.f;
#pragma unroll
    for (int p = 0; p < 32; ++p) s += W1s[tid * 33 + p] * bsel[p];
    (part ? bc32 : ba32)[tid] = s;
  }

  // v-rows of Wcomb: 1024 rows, 4 per block
#pragma unroll
  for (int rr = 0; rr < 4; ++rr) {
    const int ov = bx * 4 + rr;
    const int vh = ov >> 6, vd = ov & 63;
    const float4 v = *(const float4*)(Wqkv + (size_t)(vd * 48 + 32 + vh) * DIM + tid * 4);
    ushort4 o;
    o.x = f2bf(v.x); o.y = f2bf(v.y); o.z = f2bf(v.z); o.w = f2bf(v.w);
    *(ushort4*)(Wcomb + (size_t)(1024 + ov) * DIM + tid * 4) = o;
  }
  // x cast: 131072 float4
  {
    const int idx = bx * 256 + tid;
#pragma unroll
    for (int u = 0; u < 2; ++u) {
      const int t = u * 65536 + idx;
      const float4 v = ((const float4*)x)[t];
      ushort4 o;
      o.x = f2bf(v.x); o.y = f2bf(v.y); o.z = f2bf(v.z); o.w = f2bf(v.w);
      ((ushort4*)xb)[t] = o;
    }
  }
  // Wout cast: 262144 float4
  {
    const int idx = bx * 256 + tid;
#pragma unroll
    for (int u = 0; u < 4; ++u) {
      const int t = u * 65536 + idx;
      const float4 v = ((const float4*)Wout)[t];
      ushort4 o;
      o.x = f2bf(v.x); o.y = f2bf(v.y); o.z = f2bf(v.z); o.w = f2bf(v.w);
      ((ushort4*)Woutb)[t] = o;
    }
  }
}

// ================ kernel 2: gemm_acv (256 blocks, x2 tiles) ================
__global__ __launch_bounds__(256) void k_acv(
    const short* __restrict__ xb, const short* __restrict__ Wcomb,
    const float* __restrict__ ba32, const float* __restrict__ bc32,
    const float* __restrict__ b1,
    __half* __restrict__ a_buf, __half* __restrict__ cb_buf,
    __half* __restrict__ vT) {
  const int wave0 = blockIdx.x * 4 + (threadIdx.x >> 6);
  const int lane = threadIdx.x & 63;
  const int m = lane & 15;
  const int quad = lane >> 4;

#pragma unroll
  for (int rep = 0; rep < 2; ++rep) {
    const int wv = wave0 + rep * 1024;
    const int tm = wv >> 6;
    const int tn = wv & 63;

    const short* pa  = xb + (size_t)(tm * 16 + m) * DIM + quad * 8;
    const short* pb0 = Wcomb + (size_t)(tn * 32 + m) * DIM + quad * 8;
    const short* pb1 = pb0 + (size_t)16 * DIM;

    f32x4 acc0 = {0.f,0.f,0.f,0.f}, acc1 = {0.f,0.f,0.f,0.f};
#pragma unroll 4
    for (int k = 0; k < DIM; k += 32) {
      const bf16x8 av = *(const bf16x8*)(pa + k);
      const bf16x8 b0 = *(const bf16x8*)(pb0 + k);
      const bf16x8 b1v = *(const bf16x8*)(pb1 + k);
      acc0 = __builtin_amdgcn_mfma_f32_16x16x32_bf16(av, b0, acc0, 0, 0, 0);
      acc1 = __builtin_amdgcn_mfma_f32_16x16x32_bf16(av, b1v, acc1, 0, 0, 0);
    }

#pragma unroll
    for (int r = 0; r < 4; ++r) {
      const int n = tm * 16 + quad * 4 + r;
#pragma unroll
      for (int half = 0; half < 2; ++half) {
        const int o = tn * 32 + m + half * 16;
        const float val = half ? acc1[r] : acc0[r];
        if (o < 512) {
          const int h = o >> 5, q = o & 31;
          a_buf[((size_t)h * N_SEQ + n) * P + q] = __float2half(val + ba32[q]);
        } else if (o < 1024) {
          const int oo = o - 512, h = oo >> 5, q = oo & 31;
          cb_buf[((size_t)h * N_SEQ + n) * P + q] =
              __float2half(val + bc32[q] + b1[q]);
        } else {
          const int ov = o - 1024, h = ov >> 6, d = ov & 63;
          vT[((size_t)h * DH + d) * N_SEQ + n] = __float2half(val);
        }
      }
    }
  }
}

// =================== kernel 3: attention (256 blocks) ======================
__global__ __launch_bounds__(256) void k_attn(
    const __half* __restrict__ a_buf, const __half* __restrict__ cb_buf,
    const float* __restrict__ W2, const float* __restrict__ b2,
    const float* __restrict__ W3, const __half* __restrict__ vT,
    short* __restrict__ attnb) {
  __shared__ __align__(16) char smem[SMEM_BYTES];
  __half* probS = (__half*)smem;
  float* invS = (float*)(smem + 32 * PSTR * 2);

  const int p = blockIdx.x & 15;
  const int h = blockIdx.x >> 4;
  const int tid = threadIdx.x;
  const int w = tid >> 6;
  const int lane = tid & 63;
  const int m = lane & 15, quad = lane >> 4;

  const int tlo = p, thi = 31 - p;
  const int nlo = p + 1, nhi = 32 - p;

  {
    f16x8 w2f;
    {
      const float4* wp = (const float4*)(W2 + m * P + quad * 8);
      const float4 w0 = wp[0], w1 = wp[1];
      H8 u;
      u.h2[0] = __floats2half2_rn(w0.x, w0.y);
      u.h2[1] = __floats2half2_rn(w0.z, w0.w);
      u.h2[2] = __floats2half2_rn(w1.x, w1.y);
      u.h2[3] = __floats2half2_rn(w1.z, w1.w);
      w2f = u.v;
    }
    const float4 b2q = *(const float4*)(b2 + quad * 4);
    const float4 w3q = *(const float4*)(W3 + quad * 4);

    H8 alo[4], ahi[4];
#pragma unroll
    for (int r = 0; r < 4; ++r) {
      alo[r].v = *(const f16x8*)(a_buf + ((size_t)h * N_SEQ + tlo * 16 + 4 * w + r) * P + quad * 8);
      ahi[r].v = *(const f16x8*)(a_buf + ((size_t)h * N_SEQ + thi * 16 + 4 * w + r) * P + quad * 8);
    }

    for (int jt = 0; jt < nhi; ++jt) {
      H8 cb;
      cb.v = *(const f16x8*)(cb_buf + ((size_t)h * N_SEQ + jt * 16 + m) * P + quad * 8);
      const float q0 = rowscore(ahi[0], cb, w2f, b2q, w3q);
      const float q1 = rowscore(ahi[1], cb, w2f, b2q, w3q);
      const float q2 = rowscore(ahi[2], cb, w2f, b2q, w3q);
      const float q3 = rowscore(ahi[3], cb, w2f, b2q, w3q);
      const float fh = quadreduce4(q0, q1, q2, q3, quad);
      probS[(16 + 4 * w + quad) * PSTR + jt * 16 + m] = __float2half(fh);
      if (jt < nlo) {
        const float s0 = rowscore(alo[0], cb, w2f, b2q, w3q);
        const float s1 = rowscore(alo[1], cb, w2f, b2q, w3q);
        const float s2 = rowscore(alo[2], cb, w2f, b2q, w3q);
        const float s3 = rowscore(alo[3], cb, w2f, b2q, w3q);
        const float fl = quadreduce4(s0, s1, s2, s3, quad);
        probS[(4 * w + quad) * PSTR + jt * 16 + m] = __float2half(fl);
      }
    }
  }
  __syncthreads();

  {
    const int lr = 8 * w + (lane >> 3);
    const int c  = lane & 7;
    const int gi = (lr < 16) ? (tlo * 16 + lr) : (thi * 16 + (lr - 16));
    float mx = -1e30f;
#pragma unroll
    for (int k = 0; k < 8; ++k) {
      const int c0 = k * 64 + c * 8;
      if (c0 > gi) break;
      H8 vv; vv.v = *(const f16x8*)&probS[lr * PSTR + c0];
#pragma unroll
      for (int u = 0; u < 8; ++u) {
        const float s = __half2float(vv.h2[u >> 1].data[u & 1]);
        if (c0 + u <= gi) mx = fmaxf(mx, s);
      }
    }
#pragma unroll
    for (int msk = 1; msk < 8; msk <<= 1) mx = fmaxf(mx, __shfl_xor(mx, msk));
    float sum = 0.f;
#pragma unroll
    for (int k = 0; k < 8; ++k) {
      const int c0 = k * 64 + c * 8;
      H8 vv; vv.v = *(const f16x8*)&probS[lr * PSTR + c0];
      H8 o;
#pragma unroll
      for (int u = 0; u < 4; ++u) {
        float e0 = 0.f, e1 = 0.f;
        if (c0 + 2 * u <= gi) {
          e0 = __expf(__half2float(vv.h2[u].data[0]) - mx);
          if (c0 + 2 * u + 1 <= gi)
            e1 = __expf(__half2float(vv.h2[u].data[1]) - mx);
        }
        sum += e0 + e1;
        o.h2[u] = __floats2half2_rn(e0, e1);
      }
      *(f16x8*)&probS[lr * PSTR + c0] = o.v;
    }
#pragma unroll
    for (int msk = 1; msk < 8; msk <<= 1) sum += __shfl_xor(sum, msk);
    if (c == 0) invS[lr] = 1.f / sum;
  }
  __syncthreads();

  {
    const int d0 = w * 16;
    const __half* pb = vT + ((size_t)h * DH + d0 + m) * N_SEQ + quad * 8;
#pragma unroll
    for (int half = 0; half < 2; ++half) {
      const int lbase = half ? 16 : 0;
      const int tile = half ? thi : tlo;
      const int nk = half ? ((33 - p) >> 1) : ((p + 2) >> 1);
      f32x4 acc = {0.f, 0.f, 0.f, 0.f};
      for (int k = 0; k < nk; ++k) {
        const f16x8 a = *(const f16x8*)&probS[(lbase + m) * PSTR + k * 32 + quad * 8];
        const f16x8 b = *(const f16x8*)(pb + k * 32);
        acc = __builtin_amdgcn_mfma_f32_16x16x32_f16(a, b, acc, 0, 0, 0);
      }
#pragma unroll
      for (int r = 0; r < 4; ++r) {
        const int lrow = quad * 4 + r;
        const float val = acc[r] * invS[lbase + lrow];
        attnb[(size_t)(tile * 16 + lrow) * DIM + h * DH + d0 + m] =
            (short)f2bf(val);
      }
    }
  }
}

// ================ kernel 4: gemm_out (256 blocks, x2 tiles) ================
__global__ __launch_bounds__(256) void k_out(
    const short* __restrict__ attnb, const short* __restrict__ Woutb,
    float* __restrict__ out) {
  const int wave0 = blockIdx.x * 4 + (threadIdx.x >> 6);
  const int lane = threadIdx.x & 63;
  const int m = lane & 15, quad = lane >> 4;

#pragma unroll
  for (int rep = 0; rep < 2; ++rep) {
    const int wv = wave0 + rep * 1024;
    const int tm = wv >> 6;
    const int tn = wv & 63;

    const short* pa = attnb + (size_t)(tm * 16 + m) * DIM + quad * 8;
    const short* pb = Woutb + (size_t)(tn * 16 + m) * DIM + quad * 8;

    f32x4 acc = {0.f, 0.f, 0.f, 0.f};
#pragma unroll 4
    for (int k = 0; k < DIM; k += 32) {
      const bf16x8 a = *(const bf16x8*)(pa + k);
      const bf16x8 b = *(const bf16x8*)(pb + k);
      acc = __builtin_amdgcn_mfma_f32_16x16x32_bf16(a, b, acc, 0, 0, 0);
    }
#pragma unroll
    for (int r = 0; r < 4; ++r)
      out[(size_t)(tm * 16 + quad * 4 + r) * DIM + tn * 16 + m] = acc[r];
  }
}

// ---------------------------------------------------------------------------
extern "C" void kernel_launch(void* const* d_in, const int* in_sizes, int n_in,
                              void* d_out, int out_size, void* d_ws, size_t ws_size,
                              hipStream_t stream) {
  const float* x    = (const float*)d_in[0];
  const float* Wqkv = (const float*)d_in[1];
  const float* Wout = (const float*)d_in[2];
  const float* Wq   = (const float*)d_in[3];
  const float* bq   = (const float*)d_in[4];
  const float* Wk   = (const float*)d_in[5];
  const float* bk   = (const float*)d_in[6];
  const float* W1   = (const float*)d_in[7];
  const float* b1   = (const float*)d_in[8];
  const float* W2   = (const float*)d_in[9];
  const float* b2   = (const float*)d_in[10];
  const float* W3   = (const float*)d_in[11];
  float* out = (float*)d_out;

  float*  ws     = (float*)d_ws;
  float*  ba32   = ws;                                   // 32
  float*  bc32   = ba32 + 32;                            // 32
  __half* a_buf  = (__half*)(bc32 + 32);                 // 16*512*32
  __half* cb_buf = a_buf + (size_t)HEADS * N_SEQ * P;    // 16*512*32
  __half* vT     = cb_buf + (size_t)HEADS * N_SEQ * P;   // 16*64*512
  short*  Wcomb  = (short*)(vT + (size_t)HEADS * DH * N_SEQ); // 2048*1024
  short*  xb     = Wcomb + (size_t)2048 * DIM;           // 512*1024
  short*  Woutb  = xb + (size_t)N_SEQ * DIM;             // 1024*1024
  short*  attnb  = Woutb + (size_t)DIM * DIM;            // 512*1024

  k_prep<<<256, 256, 0, stream>>>(Wqkv, Wq, bq, Wk, bk, W1, x, Wout,
                                  Wcomb, xb, Woutb, ba32, bc32);
  k_acv<<<256, 256, 0, stream>>>(xb, Wcomb, ba32, bc32, b1,
                                 a_buf, cb_buf, vT);
  k_attn<<<256, 256, 0, stream>>>(a_buf, cb_buf, W2, b2, W3, vT, attnb);
  k_out<<<256, 256, 0, stream>>>(attnb, Woutb, out);
}

// Round 12
// 174.209 us; speedup vs baseline: 2.2669x; 1.0462x over previous
//
#include <hip/hip_runtime.h>
#include <hip/hip_bf16.h>
#include <hip/hip_fp16.h>
#include <math.h>

#define N_SEQ 512
#define DIM   1024
#define HEADS 16
#define DH    64
#define P     32
#define PSTR  520   // prob LDS row stride in halfs

typedef short    bf16x8 __attribute__((ext_vector_type(8)));
typedef _Float16 f16x8  __attribute__((ext_vector_type(8)));
typedef float    f32x4  __attribute__((ext_vector_type(4)));

__device__ inline unsigned short f2bf(float f) {
  union { float f; unsigned u; } v; v.f = f;
  unsigned r = (v.u + 0x7fffu + ((v.u >> 16) & 1u)) >> 16;
  return (unsigned short)r;
}

union H8 { f16x8 v; __half2 h2[4]; unsigned u32[4]; };

__device__ inline float rowscore(const H8& a, const H8& c, f16x8 w2f,
                                 float4 b2q, float4 w3q) {
  H8 u;
#pragma unroll
  for (int k = 0; k < 4; ++k) {
    const __half2 s = __hadd2(a.h2[k], c.h2[k]);
    union { __half2 h; unsigned u; } cv; cv.h = s;
    const unsigned msk = (cv.u >> 15) & 0x00010001u;
    u.u32[k] = cv.u & ~(msk * 0xFFFFu);          // packed relu
  }
  f32x4 acc = {0.f, 0.f, 0.f, 0.f};
  acc = __builtin_amdgcn_mfma_f32_16x16x32_f16(w2f, u.v, acc, 0, 0, 0);
  return fmaxf(acc[0] + b2q.x, 0.f) * w3q.x + fmaxf(acc[1] + b2q.y, 0.f) * w3q.y
       + fmaxf(acc[2] + b2q.z, 0.f) * w3q.z + fmaxf(acc[3] + b2q.w, 0.f) * w3q.w;
}

__device__ inline float quadreduce4(float p0, float p1, float p2, float p3,
                                    int quad) {
  const float sx = (quad & 1) ? p0 : p1;
  const float sy = (quad & 1) ? p2 : p3;
  const float rx = __shfl_xor(sx, 16);
  const float ry = __shfl_xor(sy, 16);
  const float aa = ((quad & 1) ? p1 : p0) + rx;
  const float bb = ((quad & 1) ? p3 : p2) + ry;
  const float sz = (quad & 2) ? aa : bb;
  const float rz = __shfl_xor(sz, 32);
  return ((quad & 2) ? bb : aa) + rz;
}

// ---------------------------------------------------------------------------
// prep: 768 blocks, all concurrent.
//  [0,256):  fold Wa/Wc in-block -> Wcomb a/c rows; blocks 0/128 emit biases.
//  [256,384): Wcomb v-rows.  [384,512): x cast.  [512,768): Wout cast.
// ---------------------------------------------------------------------------
__global__ __launch_bounds__(256) void k_prep(
    const float* __restrict__ Wqkv, const float* __restrict__ Wq,
    const float* __restrict__ bq, const float* __restrict__ Wk,
    const float* __restrict__ bk, const float* __restrict__ W1,
    const float* __restrict__ x, const float* __restrict__ Wout,
    short* __restrict__ Wcomb, short* __restrict__ xb,
    short* __restrict__ Woutb, float* __restrict__ ba32,
    float* __restrict__ bc32) {
  const int b = blockIdx.x, tid = threadIdx.x;
  if (b < 256) {
    __shared__ float W1s[32][33];
    __shared__ float Wqs[32][65];
    __shared__ float wsm[32][65];
    __shared__ __align__(16) float qs[64][132];
    const int part = b >> 7, rem = b & 127;
    const int h = rem >> 3, c0 = (rem & 7) * 128;
    const int grow = part * 16 + h;
    for (int idx = tid; idx < 1024; idx += 256)
      W1s[idx >> 5][idx & 31] = W1[(idx >> 5) * 64 + part * 32 + (idx & 31)];
    const float* Wsel = part ? Wk : Wq;
    for (int idx = tid; idx < 2048; idx += 256)
      Wqs[idx >> 6][idx & 63] = Wsel[idx];
    for (int idx = tid; idx < 2048; idx += 256) {
      const int d = idx >> 5, c4 = idx & 31;
      *(float4*)&qs[d][c4 * 4] =
          *(const float4*)(Wqkv + (size_t)(d * 48 + grow) * DIM + c0 + c4 * 4);
    }
    __syncthreads();
    for (int idx = tid; idx < 2048; idx += 256) {
      const int q = idx >> 6, d = idx & 63;
      float s = 0.f;
#pragma unroll
      for (int p = 0; p < 32; ++p) s += W1s[q][p] * Wqs[p][d];
      wsm[q][d] = s;
    }
    __syncthreads();
    for (int idx = tid; idx < 4096; idx += 256) {
      const int q = idx >> 7, c = idx & 127;
      float s = 0.f;
#pragma unroll
      for (int d = 0; d < 64; ++d) s += wsm[q][d] * qs[d][c];
      Wcomb[(size_t)(part * 512 + h * 32 + q) * DIM + c0 + c] = (short)f2bf(s);
    }
    if (rem == 0 && tid < 32) {
      const float* bsel = part ? bk : bq;
      float s = 0.f;
#pragma unroll
      for (int p = 0; p < 32; ++p) s += W1s[tid][p] * bsel[p];
      (part ? bc32 : ba32)[tid] = s;
    }
  } else if (b < 384) {
#pragma unroll
    for (int rr = 0; rr < 8; ++rr) {
      const int ov = (b - 256) * 8 + rr;
      const int h = ov >> 6, d = ov & 63;
      const float4 v = *(const float4*)(Wqkv + (size_t)(d * 48 + 32 + h) * DIM + tid * 4);
      ushort4 o;
      o.x = f2bf(v.x); o.y = f2bf(v.y); o.z = f2bf(v.z); o.w = f2bf(v.w);
      *(ushort4*)(Wcomb + (size_t)(1024 + ov) * DIM + tid * 4) = o;
    }
  } else if (b < 512) {
    const int idx = (b - 384) * 256 + tid;
#pragma unroll
    for (int u = 0; u < 4; ++u) {
      const int t = u * 32768 + idx;
      const float4 v = ((const float4*)x)[t];
      ushort4 o;
      o.x = f2bf(v.x); o.y = f2bf(v.y); o.z = f2bf(v.z); o.w = f2bf(v.w);
      ((ushort4*)xb)[t] = o;
    }
  } else {
    const int idx = (b - 512) * 256 + tid;
#pragma unroll
    for (int u = 0; u < 4; ++u) {
      const int t = u * 65536 + idx;
      const float4 v = ((const float4*)Wout)[t];
      ushort4 o;
      o.x = f2bf(v.x); o.y = f2bf(v.y); o.z = f2bf(v.z); o.w = f2bf(v.w);
      ((ushort4*)Woutb)[t] = o;
    }
  }
}

// ---------------------------------------------------------------------------
// gemm_acv: Y(512x2048) = xb @ Wcomb^T; scatter to fp16 a / cb(+b1) / vT.
// 512 blocks, one 16x32 tile per wave.
// ---------------------------------------------------------------------------
__global__ __launch_bounds__(256) void k_acv(
    const short* __restrict__ xb, const short* __restrict__ Wcomb,
    const float* __restrict__ ba32, const float* __restrict__ bc32,
    const float* __restrict__ b1,
    __half* __restrict__ a_buf, __half* __restrict__ cb_buf,
    __half* __restrict__ vT) {
  const int wave = blockIdx.x * 4 + (threadIdx.x >> 6);
  const int tm = wave >> 6;
  const int tn = wave & 63;
  const int lane = threadIdx.x & 63;
  const int m = lane & 15;
  const int quad = lane >> 4;

  const short* pa  = xb + (size_t)(tm * 16 + m) * DIM + quad * 8;
  const short* pb0 = Wcomb + (size_t)(tn * 32 + m) * DIM + quad * 8;
  const short* pb1 = pb0 + (size_t)16 * DIM;

  f32x4 acc0 = {0.f,0.f,0.f,0.f}, acc1 = {0.f,0.f,0.f,0.f};
#pragma unroll 4
  for (int k = 0; k < DIM; k += 32) {
    const bf16x8 av = *(const bf16x8*)(pa + k);
    const bf16x8 b0 = *(const bf16x8*)(pb0 + k);
    const bf16x8 b1v = *(const bf16x8*)(pb1 + k);
    acc0 = __builtin_amdgcn_mfma_f32_16x16x32_bf16(av, b0, acc0, 0, 0, 0);
    acc1 = __builtin_amdgcn_mfma_f32_16x16x32_bf16(av, b1v, acc1, 0, 0, 0);
  }

#pragma unroll
  for (int r = 0; r < 4; ++r) {
    const int n = tm * 16 + quad * 4 + r;
#pragma unroll
    for (int half = 0; half < 2; ++half) {
      const int o = tn * 32 + m + half * 16;
      const float val = half ? acc1[r] : acc0[r];
      if (o < 512) {
        const int h = o >> 5, q = o & 31;
        a_buf[((size_t)h * N_SEQ + n) * P + q] = __float2half(val + ba32[q]);
      } else if (o < 1024) {
        const int oo = o - 512, h = oo >> 5, q = oo & 31;
        cb_buf[((size_t)h * N_SEQ + n) * P + q] =
            __float2half(val + bc32[q] + b1[q]);
      } else {
        const int ov = o - 1024, h = ov >> 6, d = ov & 63;
        vT[((size_t)h * DH + d) * N_SEQ + n] = __float2half(val);
      }
    }
  }
}

// ---------------------------------------------------------------------------
// attention: scores (MFMA f16) -> softmax (unnorm exp in LDS) -> PV (MFMA).
// 256 blocks = (pair p, head), i-tiles {p, 31-p}, mirror-balanced.
// ---------------------------------------------------------------------------
__global__ __launch_bounds__(256) void k_attn(
    const __half* __restrict__ a_buf, const __half* __restrict__ cb_buf,
    const float* __restrict__ W2, const float* __restrict__ b2,
    const float* __restrict__ W3, const __half* __restrict__ vT,
    short* __restrict__ attnb) {
  __shared__ __align__(16) __half probS[32][PSTR];
  __shared__ float invS[32];

  const int p = blockIdx.x & 15;
  const int h = blockIdx.x >> 4;
  const int tid = threadIdx.x;
  const int w = tid >> 6;
  const int lane = tid & 63;
  const int m = lane & 15, quad = lane >> 4;

  const int tlo = p, thi = 31 - p;
  const int nlo = p + 1, nhi = 32 - p;

  {
    f16x8 w2f;
    {
      const float4* wp = (const float4*)(W2 + m * P + quad * 8);
      const float4 w0 = wp[0], w1 = wp[1];
      H8 u;
      u.h2[0] = __floats2half2_rn(w0.x, w0.y);
      u.h2[1] = __floats2half2_rn(w0.z, w0.w);
      u.h2[2] = __floats2half2_rn(w1.x, w1.y);
      u.h2[3] = __floats2half2_rn(w1.z, w1.w);
      w2f = u.v;
    }
    const float4 b2q = *(const float4*)(b2 + quad * 4);
    const float4 w3q = *(const float4*)(W3 + quad * 4);

    H8 alo[4], ahi[4];
#pragma unroll
    for (int r = 0; r < 4; ++r) {
      alo[r].v = *(const f16x8*)(a_buf + ((size_t)h * N_SEQ + tlo * 16 + 4 * w + r) * P + quad * 8);
      ahi[r].v = *(const f16x8*)(a_buf + ((size_t)h * N_SEQ + thi * 16 + 4 * w + r) * P + quad * 8);
    }

    for (int jt = 0; jt < nhi; ++jt) {
      H8 cb;
      cb.v = *(const f16x8*)(cb_buf + ((size_t)h * N_SEQ + jt * 16 + m) * P + quad * 8);
      const float q0 = rowscore(ahi[0], cb, w2f, b2q, w3q);
      const float q1 = rowscore(ahi[1], cb, w2f, b2q, w3q);
      const float q2 = rowscore(ahi[2], cb, w2f, b2q, w3q);
      const float q3 = rowscore(ahi[3], cb, w2f, b2q, w3q);
      const float fh = quadreduce4(q0, q1, q2, q3, quad);
      probS[16 + 4 * w + quad][jt * 16 + m] = __float2half(fh);
      if (jt < nlo) {
        const float s0 = rowscore(alo[0], cb, w2f, b2q, w3q);
        const float s1 = rowscore(alo[1], cb, w2f, b2q, w3q);
        const float s2 = rowscore(alo[2], cb, w2f, b2q, w3q);
        const float s3 = rowscore(alo[3], cb, w2f, b2q, w3q);
        const float fl = quadreduce4(s0, s1, s2, s3, quad);
        probS[4 * w + quad][jt * 16 + m] = __float2half(fl);
      }
    }
  }
  __syncthreads();

  {
    const int lr = 8 * w + (lane >> 3);
    const int c  = lane & 7;
    const int gi = (lr < 16) ? (tlo * 16 + lr) : (thi * 16 + (lr - 16));
    float mx = -1e30f;
#pragma unroll
    for (int k = 0; k < 8; ++k) {
      const int c0 = k * 64 + c * 8;
      if (c0 > gi) break;
      H8 vv; vv.v = *(const f16x8*)&probS[lr][c0];
#pragma unroll
      for (int u = 0; u < 8; ++u) {
        const float s = __half2float(vv.h2[u >> 1].data[u & 1]);
        if (c0 + u <= gi) mx = fmaxf(mx, s);
      }
    }
#pragma unroll
    for (int msk = 1; msk < 8; msk <<= 1) mx = fmaxf(mx, __shfl_xor(mx, msk));
    float sum = 0.f;
#pragma unroll
    for (int k = 0; k < 8; ++k) {
      const int c0 = k * 64 + c * 8;
      H8 vv; vv.v = *(const f16x8*)&probS[lr][c0];
      H8 o;
#pragma unroll
      for (int u = 0; u < 4; ++u) {
        float e0 = 0.f, e1 = 0.f;
        if (c0 + 2 * u <= gi) {
          e0 = __expf(__half2float(vv.h2[u].data[0]) - mx);
          if (c0 + 2 * u + 1 <= gi)
            e1 = __expf(__half2float(vv.h2[u].data[1]) - mx);
        }
        sum += e0 + e1;
        o.h2[u] = __floats2half2_rn(e0, e1);
      }
      *(f16x8*)&probS[lr][c0] = o.v;
    }
#pragma unroll
    for (int msk = 1; msk < 8; msk <<= 1) sum += __shfl_xor(sum, msk);
    if (c == 0) invS[lr] = 1.f / sum;
  }
  __syncthreads();

  {
    const int d0 = w * 16;
    const __half* pb = vT + ((size_t)h * DH + d0 + m) * N_SEQ + quad * 8;
#pragma unroll
    for (int half = 0; half < 2; ++half) {
      const int lbase = half ? 16 : 0;
      const int tile = half ? thi : tlo;
      const int nk = half ? ((33 - p) >> 1) : ((p + 2) >> 1);
      f32x4 acc = {0.f, 0.f, 0.f, 0.f};
      for (int k = 0; k < nk; ++k) {
        const f16x8 a = *(const f16x8*)&probS[lbase + m][k * 32 + quad * 8];
        const f16x8 b = *(const f16x8*)(pb + k * 32);
        acc = __builtin_amdgcn_mfma_f32_16x16x32_f16(a, b, acc, 0, 0, 0);
      }
#pragma unroll
      for (int r = 0; r < 4; ++r) {
        const int lrow = quad * 4 + r;
        const float val = acc[r] * invS[lbase + lrow];
        attnb[(size_t)(tile * 16 + lrow) * DIM + h * DH + d0 + m] =
            (short)f2bf(val);
      }
    }
  }
}

// ---------------------------------------------------------------------------
// output GEMM: out(512x1024) = attnb @ Woutb^T. 512 blocks, 16x16 tile/wave.
// ---------------------------------------------------------------------------
__global__ __launch_bounds__(256) void k_out(
    const short* __restrict__ attnb, const short* __restrict__ Woutb,
    float* __restrict__ out) {
  const int wave = blockIdx.x * 4 + (threadIdx.x >> 6);
  const int tm = wave >> 6;
  const int tn = wave & 63;
  const int lane = threadIdx.x & 63;
  const int m = lane & 15, quad = lane >> 4;

  const short* pa = attnb + (size_t)(tm * 16 + m) * DIM + quad * 8;
  const short* pb = Woutb + (size_t)(tn * 16 + m) * DIM + quad * 8;

  f32x4 acc = {0.f, 0.f, 0.f, 0.f};
#pragma unroll 4
  for (int k = 0; k < DIM; k += 32) {
    const bf16x8 a = *(const bf16x8*)(pa + k);
    const bf16x8 b = *(const bf16x8*)(pb + k);
    acc = __builtin_amdgcn_mfma_f32_16x16x32_bf16(a, b, acc, 0, 0, 0);
  }
#pragma unroll
  for (int r = 0; r < 4; ++r)
    out[(size_t)(tm * 16 + quad * 4 + r) * DIM + tn * 16 + m] = acc[r];
}

// ---------------------------------------------------------------------------
extern "C" void kernel_launch(void* const* d_in, const int* in_sizes, int n_in,
                              void* d_out, int out_size, void* d_ws, size_t ws_size,
                              hipStream_t stream) {
  const float* x    = (const float*)d_in[0];
  const float* Wqkv = (const float*)d_in[1];
  const float* Wout = (const float*)d_in[2];
  const float* Wq   = (const float*)d_in[3];
  const float* bq   = (const float*)d_in[4];
  const float* Wk   = (const float*)d_in[5];
  const float* bk   = (const float*)d_in[6];
  const float* W1   = (const float*)d_in[7];
  const float* b1   = (const float*)d_in[8];
  const float* W2   = (const float*)d_in[9];
  const float* b2   = (const float*)d_in[10];
  const float* W3   = (const float*)d_in[11];
  float* out = (float*)d_out;

  float*  ws     = (float*)d_ws;
  float*  ba32   = ws;                                   // 32
  float*  bc32   = ba32 + 32;                            // 32
  __half* a_buf  = (__half*)(bc32 + 32);                 // 16*512*32
  __half* cb_buf = a_buf + (size_t)HEADS * N_SEQ * P;    // 16*512*32
  __half* vT     = cb_buf + (size_t)HEADS * N_SEQ * P;   // 16*64*512
  short*  Wcomb  = (short*)(vT + (size_t)HEADS * DH * N_SEQ); // 2048*1024
  short*  xb     = Wcomb + (size_t)2048 * DIM;           // 512*1024
  short*  Woutb  = xb + (size_t)N_SEQ * DIM;             // 1024*1024
  short*  attnb  = Woutb + (size_t)DIM * DIM;            // 512*1024

  k_prep<<<768, 256, 0, stream>>>(Wqkv, Wq, bq, Wk, bk, W1, x, Wout,
                                  Wcomb, xb, Woutb, ba32, bc32);
  k_acv<<<512, 256, 0, stream>>>(xb, Wcomb, ba32, bc32, b1,
                                 a_buf, cb_buf, vT);
  k_attn<<<256, 256, 0, stream>>>(a_buf, cb_buf, W2, b2, W3, vT, attnb);
  k_out<<<512, 256, 0, stream>>>(attnb, Woutb, out);
}